// Round 1
// baseline (501.904 us; speedup 1.0000x reference)
//
#include <hip/hip_runtime.h>
#include <hip/hip_bf16.h>

// DTM decoder, fp32 in/out. Round-5 structure:
//   K0 prep        : temb fp32 -> A_hi/A_lo bf16; zero rowsum[512]
//   K1 gemm_logits : BM=128 BN=128 BK=64, 512 thr (8 waves 4m x 2n), 128KB LDS
//                    DOUBLE-BUFFERED 2-phase schedule: STAGE(t+1) issued before
//                    compute(t), one barrier per K-step (GLDS latency hidden
//                    under MFMA). 3-term bf16 split (Ah@Bh + Ah@Bl + Al@Bh).
//                    setprio(1) around MFMA clusters. Chunked-bijective XCD
//                    swizzle (m204) for W L2 locality.
//                    Epilogue: P-hat=exp(l-180), atomicAdd rowsums, P-hat^T bf16.
//   K3 build_theta2: T2[i, t_i*50+kap] = theta[i,kap]/rowsum -> (256,512) bf16
//   K4 gemm_out    : out(256,50000)fp32 = T2 @ P-hat — pure GLDS+b128 GEMM.
// ws: Pt(50048x512 bf16) | rowsum 2KB | a_hi 1MB | a_lo 1MB | T2 256KB ~53.5MB

typedef __bf16 bf16_t;
typedef __bf16 bf16x4 __attribute__((ext_vector_type(4)));
typedef __bf16 bf16x8 __attribute__((ext_vector_type(8)));
typedef float f32x4 __attribute__((ext_vector_type(4)));

typedef __attribute__((address_space(1))) void gvoid;
typedef __attribute__((address_space(3))) void svoid;
#define GLDS(SRC, DST) \
    __builtin_amdgcn_global_load_lds((gvoid*)(SRC), (svoid*)(DST), 16, 0, 0)
#define MFMA16(A, B, C) __builtin_amdgcn_mfma_f32_16x16x32_bf16((A), (B), (C), 0, 0, 0)

#define SHIFT 180.0f
#define TTS 40  // per-wave transpose stride (32 k + 8 pad, 16B-aligned rows)

__device__ __forceinline__ void cvt8(float4 a, float4 b, bf16x8& h, bf16x8& l)
{
    float f[8] = {a.x, a.y, a.z, a.w, b.x, b.y, b.z, b.w};
#pragma unroll
    for (int j = 0; j < 8; ++j) {
        bf16_t hh = (bf16_t)f[j];
        h[j] = hh;
        l[j] = (bf16_t)(f[j] - (float)hh);
    }
}

// ---------------- K0: split A fp32 -> (hi,lo) bf16; zero rowsum ----------
__global__ void prep(const float* __restrict__ x, bf16_t* __restrict__ hi,
                     bf16_t* __restrict__ lo, float* __restrict__ rsum)
{
    int i = blockIdx.x * 256 + threadIdx.x;
    if (i < 512) rsum[i] = 0.f;
    if (i < 512000) {
        float v = x[i];
        bf16_t h = (bf16_t)v;
        hi[i] = h;
        lo[i] = (bf16_t)(v - (float)h);
    }
}

// ---------------- K1: 128x128 tile, dbuf 2-phase, 3-term split ------------
// grid: 1564 linear blocks = 4 mtiles x 391 ntiles, XCD-chunk swizzled.
__global__ __launch_bounds__(512, 2)
void gemm_logits(const bf16_t* __restrict__ Ahi, const bf16_t* __restrict__ Alo,
                 const float* __restrict__ W, bf16_t* __restrict__ Pt,
                 float* __restrict__ Rsum)
{
    // 2 buffers x (AsH 16K | AsL 16K | BsH 16K | BsL 16K) = 128 KB
    __shared__ __align__(16) bf16_t sm[65536];

    const int tid = threadIdx.x;
    const int wv = tid >> 6, lane = tid & 63;
    const int wm = wv >> 1, wn = wv & 1;       // 4m x 2n wave grid

    // chunked-bijective XCD swizzle (nwg=1564 = 8*195+4 -> q=195, r=4):
    // XCD x gets a contiguous nid range; m varies fastest within it.
    const int lin = blockIdx.x;
    const int xcd = lin & 7, wi = lin >> 3;
    const int nid = (xcd < 4 ? xcd * 196 : 784 + (xcd - 4) * 195) + wi;
    const int bm0 = (nid & 3) * 128;
    const int bn0 = (nid >> 2) * 128;

    const int lrow = lane & 15, q = lane >> 4;
    const int srow = lane >> 3, sgrp = (lane & 7) ^ srow;

    // W staging role: 4 threads/row, 128 rows, 16 consecutive floats each
    const int wrow_l = tid >> 2;                // 0..127
    int wrow_g = bn0 + wrow_l; if (wrow_g > 49999) wrow_g = 49999;
    const int kq = tid & 3;                     // 16-float chunk
    const float4* wp = (const float4*)(W + (long)wrow_g * 1024 + kq * 16);
    const int kga = kq * 2;
    const int so_a = wrow_l * 64 + ((kga ^ (wrow_l & 7)) * 8);
    const int so_b = wrow_l * 64 + (((kga + 1) ^ (wrow_l & 7)) * 8);

    f32x4 acc[2][4] = {};
    float4 wnx[4];

    // ---- prologue: stage t=0 into buf 0 ----
#pragma unroll
    for (int j = 0; j < 4; ++j) wnx[j] = wp[j];
#pragma unroll
    for (int cc = 0; cc < 2; ++cc) {
        const int ch = wv * 2 + cc;             // 8-row chunk id, 0..15
        int ar = bm0 + ch * 8 + srow; if (ar > 499) ar = 499;
        GLDS(Ahi + (long)ar * 1024 + sgrp * 8, sm + ch * 512);
        GLDS(Alo + (long)ar * 1024 + sgrp * 8, sm + 8192 + ch * 512);
    }
    {
        bf16x8 h0, l0, h1, l1;
        cvt8(wnx[0], wnx[1], h0, l0);
        cvt8(wnx[2], wnx[3], h1, l1);
        *(bf16x8*)(sm + 16384 + so_a) = h0;
        *(bf16x8*)(sm + 24576 + so_a) = l0;
        *(bf16x8*)(sm + 16384 + so_b) = h1;
        *(bf16x8*)(sm + 24576 + so_b) = l1;
    }
    __syncthreads();

    for (int t = 0; t < 16; ++t) {
        const int cb = t & 1, nb = cb ^ 1;
        bf16_t* AsH = sm + cb * 32768;
        bf16_t* AsL = AsH + 8192;
        bf16_t* BsH = AsH + 16384;
        bf16_t* BsL = AsH + 24576;

        // ---- STAGE(t+1): issue loads BEFORE compute (latency hidden) ----
        if (t < 15) {
            const int o = (t + 1) * 16;         // float4 offset of next k-step
#pragma unroll
            for (int j = 0; j < 4; ++j) wnx[j] = wp[o + j];
            bf16_t* nAsH = sm + nb * 32768;
            bf16_t* nAsL = nAsH + 8192;
            const int k0n = (t + 1) * 64;
#pragma unroll
            for (int cc = 0; cc < 2; ++cc) {
                const int ch = wv * 2 + cc;
                int ar = bm0 + ch * 8 + srow; if (ar > 499) ar = 499;
                GLDS(Ahi + (long)ar * 1024 + k0n + sgrp * 8, nAsH + ch * 512);
                GLDS(Alo + (long)ar * 1024 + k0n + sgrp * 8, nAsL + ch * 512);
            }
        }

        // ---- compute on buf cb ----
#pragma unroll
        for (int kk = 0; kk < 2; ++kk) {
            const int kg = kk * 4 + q;
            bf16x8 ah[2], al[2], bh[4], bl[4];
#pragma unroll
            for (int a = 0; a < 2; ++a) {
                const int row = wm * 32 + a * 16 + lrow;
                const int off = row * 64 + ((kg ^ (row & 7)) * 8);
                ah[a] = *(const bf16x8*)(AsH + off);
                al[a] = *(const bf16x8*)(AsL + off);
            }
#pragma unroll
            for (int b = 0; b < 4; ++b) {
                const int n = wn * 64 + b * 16 + lrow;
                const int off = n * 64 + ((kg ^ (n & 7)) * 8);
                bh[b] = *(const bf16x8*)(BsH + off);
                bl[b] = *(const bf16x8*)(BsL + off);
            }
            __builtin_amdgcn_s_setprio(1);
#pragma unroll
            for (int a = 0; a < 2; ++a)
#pragma unroll
                for (int b = 0; b < 4; ++b) {
                    acc[a][b] = MFMA16(ah[a], bh[b], acc[a][b]);
                    acc[a][b] = MFMA16(ah[a], bl[b], acc[a][b]);
                    acc[a][b] = MFMA16(al[a], bh[b], acc[a][b]);
                }
            __builtin_amdgcn_s_setprio(0);
        }

        // ---- W split for t+1 -> next buf (after MFMA; vmcnt covered) ----
        if (t < 15) {
            bf16_t* nBsH = sm + nb * 32768 + 16384;
            bf16_t* nBsL = nBsH + 8192;
            bf16x8 h0, l0, h1, l1;
            cvt8(wnx[0], wnx[1], h0, l0);
            cvt8(wnx[2], wnx[3], h1, l1);
            *(bf16x8*)(nBsH + so_a) = h0;
            *(bf16x8*)(nBsL + so_a) = l0;
            *(bf16x8*)(nBsH + so_b) = h1;
            *(bf16x8*)(nBsL + so_b) = l1;
        }
        __syncthreads();
    }

    // ---- epilogue: exp, rowsum atomics, P-hat^T store ----
    // wave (wm,wn) owns rows [bm0+wm*32, +32), cols [bn0+wn*64, +64)
#pragma unroll
    for (int a = 0; a < 2; ++a) {
        float rs[4] = {0.f, 0.f, 0.f, 0.f};
#pragma unroll
        for (int b = 0; b < 4; ++b) {
            const bool cok = (bn0 + wn * 64 + b * 16 + lrow) < 50000;
#pragma unroll
            for (int r = 0; r < 4; ++r) {
                const float e = __expf(acc[a][b][r] - SHIFT);
                acc[a][b][r] = e;
                if (cok) rs[r] += e;
            }
        }
#pragma unroll
        for (int r = 0; r < 4; ++r) {
            float v = rs[r];
            v += __shfl_xor(v, 1, 16);
            v += __shfl_xor(v, 2, 16);
            v += __shfl_xor(v, 4, 16);
            v += __shfl_xor(v, 8, 16);
            const int row = bm0 + wm * 32 + a * 16 + q * 4 + r;
            if (lrow == 0 && row < 500) atomicAdd(Rsum + row, v);
        }
    }
    // per-wave transpose: Tt[v_loc 0..63][k_loc 0..31]; 8 waves x 5120 B
    // lives in buf0 region, all reads of it completed before final barrier
    bf16_t* Tt = sm + wv * (64 * TTS);
#pragma unroll
    for (int a = 0; a < 2; ++a)
#pragma unroll
        for (int b = 0; b < 4; ++b) {
            bf16x4 p;
#pragma unroll
            for (int r = 0; r < 4; ++r) p[r] = (bf16_t)acc[a][b][r];
            *(bf16x4*)(Tt + (b * 16 + lrow) * TTS + a * 16 + q * 4) = p;
        }
    // coalesced store: 4 lanes cover one v-row's 64B (32 k-elems)
    const long kbase = bm0 + wm * 32;
    const int cbase = bn0 + wn * 64;
#pragma unroll
    for (int it = 0; it < 4; ++it) {
        const int u = it * 64 + lane;
        const int vl = u >> 2, ck = u & 3;
        bf16x8 d = *(const bf16x8*)(Tt + vl * TTS + ck * 8);
        *(bf16x8*)(Pt + (long)(cbase + vl) * 512 + kbase + ck * 8) = d;
    }
}

// ---------------- K3: T2[i,r] = theta[i,r-50t]/rowsum[r] (else 0) ---------
__global__ void build_theta2(const float* __restrict__ theta,
                             const int* __restrict__ tidx,
                             const float* __restrict__ rsum,
                             bf16_t* __restrict__ T2)
{
    const int i = blockIdx.x, r = threadIdx.x;      // r in [0,512)
    const int base = tidx[i] * 50;
    bf16_t v = (bf16_t)0.0f;
    if (r >= base && r < base + 50)
        v = (bf16_t)(theta[i * 50 + (r - base)] / rsum[r]);
    T2[i * 512 + r] = v;
}

// ---------------- K4: out(256x50000)fp32 = T2(256x512) @ P-hat ------------
__global__ __launch_bounds__(256, 4)
void gemm_out(const bf16_t* __restrict__ T2, const bf16_t* __restrict__ Pt,
              float* __restrict__ out)
{
    __shared__ __align__(16) bf16_t As[256 * 64];   // 32 KB
    __shared__ __align__(16) bf16_t Bs[64 * 64];    // 8 KB
    const int tid = threadIdx.x;
    const int wave = tid >> 6, lane = tid & 63;
    const int bn0 = blockIdx.x * 64;
    const int lrow = lane & 15, q = lane >> 4;
    const int srow = lane >> 3, sgrp = (lane & 7) ^ srow;

    f32x4 acc[4][4] = {};

    for (int k0 = 0; k0 < 512; k0 += 64) {
#pragma unroll
        for (int cc = 0; cc < 8; ++cc) {            // A: 32 chunks total
            const int ch = wave * 8 + cc;
            GLDS(T2 + (ch * 8 + srow) * 512 + k0 + sgrp * 8, As + ch * 512);
        }
#pragma unroll
        for (int cc = 0; cc < 2; ++cc) {            // B: 8 chunks total
            const int ch = wave * 2 + cc;
            const long brow = bn0 + ch * 8 + srow;  // Pt padded to 50048 rows
            GLDS(Pt + brow * 512 + k0 + sgrp * 8, Bs + ch * 512);
        }
        __syncthreads();
#pragma unroll
        for (int kk = 0; kk < 2; ++kk) {
            const int kg = kk * 4 + q;
            bf16x8 af[4], bfr[4];
#pragma unroll
            for (int a = 0; a < 4; ++a) {
                const int row = wave * 64 + a * 16 + lrow;
                af[a] = *(const bf16x8*)(As + row * 64 + ((kg ^ (row & 7)) * 8));
            }
#pragma unroll
            for (int b = 0; b < 4; ++b) {
                const int n = b * 16 + lrow;
                bfr[b] = *(const bf16x8*)(Bs + n * 64 + ((kg ^ (n & 7)) * 8));
            }
#pragma unroll
            for (int a = 0; a < 4; ++a)
#pragma unroll
                for (int b = 0; b < 4; ++b)
                    acc[a][b] = MFMA16(af[a], bfr[b], acc[a][b]);
        }
        __syncthreads();
    }
#pragma unroll
    for (int a = 0; a < 4; ++a) {
        const int row0 = wave * 64 + a * 16 + q * 4;
#pragma unroll
        for (int b = 0; b < 4; ++b) {
            const int col = bn0 + b * 16 + lrow;
            if (col < 50000) {
#pragma unroll
                for (int r = 0; r < 4; ++r)
                    out[(long)(row0 + r) * 50000 + col] = acc[a][b][r];
            }
        }
    }
}

extern "C" void kernel_launch(void* const* d_in, const int* in_sizes, int n_in,
                              void* d_out, int out_size, void* d_ws, size_t ws_size,
                              hipStream_t stream)
{
    const float* theta = (const float*)d_in[0];   // (256,50) fp32
    const float* wemb  = (const float*)d_in[1];   // (50000,1024) fp32
    const float* temb  = (const float*)d_in[2];   // (500,1024) fp32
    const int*   tidx  = (const int*)d_in[3];     // (256,)
    float* out = (float*)d_out;                   // (256,50000) fp32

    char* ws = (char*)d_ws;
    bf16_t* Pt    = (bf16_t*)ws;                          // 50048*512*2 = 51,249,152
    float*  rsum  = (float*)(ws + 51249152);              // 2 KB
    bf16_t* a_hi  = (bf16_t*)(ws + 51251200);             // 1,024,000
    bf16_t* a_lo  = (bf16_t*)(ws + 52275200);             // 1,024,000
    bf16_t* T2    = (bf16_t*)(ws + 53299200);             // 262,144

    prep        <<<dim3(2000), 256, 0, stream>>>(temb, a_hi, a_lo, rsum);
    gemm_logits <<<dim3(1564), 512, 0, stream>>>(a_hi, a_lo, wemb, Pt, rsum);
    build_theta2<<<dim3(256),  512, 0, stream>>>(theta, tidx, rsum, T2);
    gemm_out    <<<dim3(782),  256, 0, stream>>>(T2, Pt, out);
}

// Round 2
// 486.950 us; speedup vs baseline: 1.0307x; 1.0307x over previous
//
#include <hip/hip_runtime.h>
#include <hip/hip_bf16.h>

// DTM decoder, fp32 in/out. Round-6 structure:
//   K0 prep        : temb fp32 -> A_hi/A_lo bf16; zero rowsum[512]
//   K1 gemm_logits : BM=128 BN=128 BK=64, 512 thr (8 waves 4m x 2n), 128KB LDS
//                    dbuf + COUNTED vmcnt(4) + RAW s_barrier: A-tile GLDS for
//                    t+1 stays in flight ACROSS the barrier (T3+T4, m218);
//                    never drains to 0 in the main loop. W fp32 reg-prefetch
//                    (t+1) issued before the barrier, split->LDS after MFMA.
//                    3-term bf16 split (Ah@Bh + Ah@Bl + Al@Bh). setprio around
//                    MFMA. Chunked-bijective XCD swizzle (m204).
//                    Epilogue: P-hat=exp(l-180), atomicAdd rowsums, P-hat^T bf16.
//   K3 build_theta2: T2[i, t_i*50+kap] = theta[i,kap]/rowsum -> (256,512) bf16
//   K4 gemm_out    : out(256,50000)fp32 = T2 @ P-hat — pure GLDS+b128 GEMM.
// ws: Pt(50048x512 bf16) | rowsum 2KB | a_hi 1MB | a_lo 1MB | T2 256KB ~53.5MB

typedef __bf16 bf16_t;
typedef __bf16 bf16x4 __attribute__((ext_vector_type(4)));
typedef __bf16 bf16x8 __attribute__((ext_vector_type(8)));
typedef float f32x4 __attribute__((ext_vector_type(4)));

typedef __attribute__((address_space(1))) void gvoid;
typedef __attribute__((address_space(3))) void svoid;
#define GLDS(SRC, DST) \
    __builtin_amdgcn_global_load_lds((gvoid*)(SRC), (svoid*)(DST), 16, 0, 0)
#define MFMA16(A, B, C) __builtin_amdgcn_mfma_f32_16x16x32_bf16((A), (B), (C), 0, 0, 0)
#define SBAR0() __builtin_amdgcn_sched_barrier(0)

#define SHIFT 180.0f
#define TTS 40  // per-wave transpose stride (32 k + 8 pad, 16B-aligned rows)

__device__ __forceinline__ void cvt8(float4 a, float4 b, bf16x8& h, bf16x8& l)
{
    float f[8] = {a.x, a.y, a.z, a.w, b.x, b.y, b.z, b.w};
#pragma unroll
    for (int j = 0; j < 8; ++j) {
        bf16_t hh = (bf16_t)f[j];
        h[j] = hh;
        l[j] = (bf16_t)(f[j] - (float)hh);
    }
}

// ---------------- K0: split A fp32 -> (hi,lo) bf16; zero rowsum ----------
__global__ void prep(const float* __restrict__ x, bf16_t* __restrict__ hi,
                     bf16_t* __restrict__ lo, float* __restrict__ rsum)
{
    int i = blockIdx.x * 256 + threadIdx.x;
    if (i < 512) rsum[i] = 0.f;
    if (i < 512000) {
        float v = x[i];
        bf16_t h = (bf16_t)v;
        hi[i] = h;
        lo[i] = (bf16_t)(v - (float)h);
    }
}

// ---------------- K1: 128x128 tile, dbuf + counted vmcnt ------------------
// grid: 1564 linear blocks = 4 mtiles x 391 ntiles, XCD-chunk swizzled.
__global__ __launch_bounds__(512, 2)
void gemm_logits(const bf16_t* __restrict__ Ahi, const bf16_t* __restrict__ Alo,
                 const float* __restrict__ W, bf16_t* __restrict__ Pt,
                 float* __restrict__ Rsum)
{
    // 2 buffers x (AsH 16K | AsL 16K | BsH 16K | BsL 16K) = 128 KB
    __shared__ __align__(16) bf16_t sm[65536];

    const int tid = threadIdx.x;
    const int wv = tid >> 6, lane = tid & 63;
    const int wm = wv >> 1, wn = wv & 1;       // 4m x 2n wave grid

    // chunked-bijective XCD swizzle (nwg=1564 = 8*195+4 -> q=195, r=4)
    const int lin = blockIdx.x;
    const int xcd = lin & 7, wi = lin >> 3;
    const int nid = (xcd < 4 ? xcd * 196 : 784 + (xcd - 4) * 195) + wi;
    const int bm0 = (nid & 3) * 128;
    const int bn0 = (nid >> 2) * 128;

    const int lrow = lane & 15, q = lane >> 4;
    const int srow = lane >> 3, sgrp = (lane & 7) ^ srow;

    // W staging role: 4 threads/row, 128 rows, 16 consecutive floats each
    const int wrow_l = tid >> 2;                // 0..127
    int wrow_g = bn0 + wrow_l; if (wrow_g > 49999) wrow_g = 49999;
    const int kq = tid & 3;                     // 16-float chunk
    const float4* wp = (const float4*)(W + (long)wrow_g * 1024 + kq * 16);
    const int kga = kq * 2;
    const int so_a = wrow_l * 64 + ((kga ^ (wrow_l & 7)) * 8);
    const int so_b = wrow_l * 64 + (((kga + 1) ^ (wrow_l & 7)) * 8);

    f32x4 acc[2][4] = {};

    // ---- prologue: W(0) regs; GLDS A(0)->buf0; cvt W(0)->B(buf0) ----
    {
        float4 w0[4];
#pragma unroll
        for (int j = 0; j < 4; ++j) w0[j] = wp[j];
#pragma unroll
        for (int cc = 0; cc < 2; ++cc) {
            const int ch = wv * 2 + cc;         // 8-row chunk id, 0..15
            int ar = bm0 + ch * 8 + srow; if (ar > 499) ar = 499;
            GLDS(Ahi + (long)ar * 1024 + sgrp * 8, sm + ch * 512);
            GLDS(Alo + (long)ar * 1024 + sgrp * 8, sm + 8192 + ch * 512);
        }
        bf16x8 h0, l0, h1, l1;                  // compiler waits W(0) only
        cvt8(w0[0], w0[1], h0, l0);
        cvt8(w0[2], w0[3], h1, l1);
        *(bf16x8*)(sm + 16384 + so_a) = h0;
        *(bf16x8*)(sm + 24576 + so_a) = l0;
        *(bf16x8*)(sm + 16384 + so_b) = h1;
        *(bf16x8*)(sm + 24576 + so_b) = l1;
    }
    // NOTE: no barrier here — iter-0's counted wait + barrier publishes both
    // the A(0) GLDS (vmcnt) and the B(0) ds_writes (lgkmcnt) for all waves.

    // ---- main loop: t = 0..14 stage t+1; t=15 peeled below ----
    for (int t = 0; t < 15; ++t) {
        const int cb = t & 1, nb = cb ^ 1;
        bf16_t* AsH = sm + cb * 32768;
        bf16_t* AsL = AsH + 8192;
        bf16_t* BsH = AsH + 16384;
        bf16_t* BsL = AsH + 24576;

        // (a) W regs for t+1 — must be issued BEFORE the counted wait
        float4 wnx[4];
        {
            const int o = (t + 1) * 16;
#pragma unroll
            for (int j = 0; j < 4; ++j) wnx[j] = wp[o + j];
        }
        SBAR0();
        // (b) counted wait: drains A(t)'s 4 GLDS, keeps W(t+1)'s 4 in flight.
        //     lgkmcnt(0) publishes last iter's B ds_writes. Raw barrier: the
        //     compiler does NOT add vmcnt(0) here (unlike __syncthreads).
        asm volatile("s_waitcnt vmcnt(4) lgkmcnt(0)" ::: "memory");
        SBAR0();
        __builtin_amdgcn_s_barrier();
        SBAR0();
        // (c) GLDS A(t+1) -> buf nb (after barrier: nobody reads nb anymore)
        {
            bf16_t* nAsH = sm + nb * 32768;
            bf16_t* nAsL = nAsH + 8192;
            const int k0n = (t + 1) * 64;
#pragma unroll
            for (int cc = 0; cc < 2; ++cc) {
                const int ch = wv * 2 + cc;
                int ar = bm0 + ch * 8 + srow; if (ar > 499) ar = 499;
                GLDS(Ahi + (long)ar * 1024 + k0n + sgrp * 8, nAsH + ch * 512);
                GLDS(Alo + (long)ar * 1024 + k0n + sgrp * 8, nAsL + ch * 512);
            }
        }
        SBAR0();
        // (d) compute on buf cb
#pragma unroll
        for (int kk = 0; kk < 2; ++kk) {
            const int kg = kk * 4 + q;
            bf16x8 ah[2], al[2], bh[4], bl[4];
#pragma unroll
            for (int a = 0; a < 2; ++a) {
                const int row = wm * 32 + a * 16 + lrow;
                const int off = row * 64 + ((kg ^ (row & 7)) * 8);
                ah[a] = *(const bf16x8*)(AsH + off);
                al[a] = *(const bf16x8*)(AsL + off);
            }
#pragma unroll
            for (int b = 0; b < 4; ++b) {
                const int n = wn * 64 + b * 16 + lrow;
                const int off = n * 64 + ((kg ^ (n & 7)) * 8);
                bh[b] = *(const bf16x8*)(BsH + off);
                bl[b] = *(const bf16x8*)(BsL + off);
            }
            __builtin_amdgcn_s_setprio(1);
#pragma unroll
            for (int a = 0; a < 2; ++a)
#pragma unroll
                for (int b = 0; b < 4; ++b) {
                    acc[a][b] = MFMA16(ah[a], bh[b], acc[a][b]);
                    acc[a][b] = MFMA16(ah[a], bl[b], acc[a][b]);
                    acc[a][b] = MFMA16(al[a], bh[b], acc[a][b]);
                }
            __builtin_amdgcn_s_setprio(0);
        }
        // (e) W(t+1) split -> B of buf nb. Compiler inserts vmcnt(4) for the
        //     wnx regs (the 4 A(t+1) GLDS are newer — they stay in flight).
        {
            bf16_t* nBsH = sm + nb * 32768 + 16384;
            bf16_t* nBsL = nBsH + 8192;
            bf16x8 h0, l0, h1, l1;
            cvt8(wnx[0], wnx[1], h0, l0);
            cvt8(wnx[2], wnx[3], h1, l1);
            *(bf16x8*)(nBsH + so_a) = h0;
            *(bf16x8*)(nBsL + so_a) = l0;
            *(bf16x8*)(nBsH + so_b) = h1;
            *(bf16x8*)(nBsL + so_b) = l1;
        }
    }

    // ---- peeled final step t=15 (cb = 1): full drain, no staging ----
    {
        bf16_t* AsH = sm + 32768;
        bf16_t* AsL = AsH + 8192;
        bf16_t* BsH = AsH + 16384;
        bf16_t* BsL = AsH + 24576;
        asm volatile("s_waitcnt vmcnt(0) lgkmcnt(0)" ::: "memory");
        SBAR0();
        __builtin_amdgcn_s_barrier();
        SBAR0();
#pragma unroll
        for (int kk = 0; kk < 2; ++kk) {
            const int kg = kk * 4 + q;
            bf16x8 ah[2], al[2], bh[4], bl[4];
#pragma unroll
            for (int a = 0; a < 2; ++a) {
                const int row = wm * 32 + a * 16 + lrow;
                const int off = row * 64 + ((kg ^ (row & 7)) * 8);
                ah[a] = *(const bf16x8*)(AsH + off);
                al[a] = *(const bf16x8*)(AsL + off);
            }
#pragma unroll
            for (int b = 0; b < 4; ++b) {
                const int n = wn * 64 + b * 16 + lrow;
                const int off = n * 64 + ((kg ^ (n & 7)) * 8);
                bh[b] = *(const bf16x8*)(BsH + off);
                bl[b] = *(const bf16x8*)(BsL + off);
            }
            __builtin_amdgcn_s_setprio(1);
#pragma unroll
            for (int a = 0; a < 2; ++a)
#pragma unroll
                for (int b = 0; b < 4; ++b) {
                    acc[a][b] = MFMA16(ah[a], bh[b], acc[a][b]);
                    acc[a][b] = MFMA16(ah[a], bl[b], acc[a][b]);
                    acc[a][b] = MFMA16(al[a], bh[b], acc[a][b]);
                }
            __builtin_amdgcn_s_setprio(0);
        }
    }

    // ---- epilogue: exp, rowsum atomics, P-hat^T store ----
    // wave (wm,wn) owns rows [bm0+wm*32, +32), cols [bn0+wn*64, +64)
#pragma unroll
    for (int a = 0; a < 2; ++a) {
        float rs[4] = {0.f, 0.f, 0.f, 0.f};
#pragma unroll
        for (int b = 0; b < 4; ++b) {
            const bool cok = (bn0 + wn * 64 + b * 16 + lrow) < 50000;
#pragma unroll
            for (int r = 0; r < 4; ++r) {
                const float e = __expf(acc[a][b][r] - SHIFT);
                acc[a][b][r] = e;
                if (cok) rs[r] += e;
            }
        }
#pragma unroll
        for (int r = 0; r < 4; ++r) {
            float v = rs[r];
            v += __shfl_xor(v, 1, 16);
            v += __shfl_xor(v, 2, 16);
            v += __shfl_xor(v, 4, 16);
            v += __shfl_xor(v, 8, 16);
            const int row = bm0 + wm * 32 + a * 16 + q * 4 + r;
            if (lrow == 0 && row < 500) atomicAdd(Rsum + row, v);
        }
    }
    // per-wave transpose in buf0 region (last compute used buf1 — disjoint,
    // and each wave only touches its own Tt slice -> wave-local ordering ok)
    bf16_t* Tt = sm + wv * (64 * TTS);
#pragma unroll
    for (int a = 0; a < 2; ++a)
#pragma unroll
        for (int b = 0; b < 4; ++b) {
            bf16x4 p;
#pragma unroll
            for (int r = 0; r < 4; ++r) p[r] = (bf16_t)acc[a][b][r];
            *(bf16x4*)(Tt + (b * 16 + lrow) * TTS + a * 16 + q * 4) = p;
        }
    // coalesced store: 4 lanes cover one v-row's 64B (32 k-elems)
    const long kbase = bm0 + wm * 32;
    const int cbase = bn0 + wn * 64;
#pragma unroll
    for (int it = 0; it < 4; ++it) {
        const int u = it * 64 + lane;
        const int vl = u >> 2, ck = u & 3;
        bf16x8 d = *(const bf16x8*)(Tt + vl * TTS + ck * 8);
        *(bf16x8*)(Pt + (long)(cbase + vl) * 512 + kbase + ck * 8) = d;
    }
}

// ---------------- K3: T2[i,r] = theta[i,r-50t]/rowsum[r] (else 0) ---------
__global__ void build_theta2(const float* __restrict__ theta,
                             const int* __restrict__ tidx,
                             const float* __restrict__ rsum,
                             bf16_t* __restrict__ T2)
{
    const int i = blockIdx.x, r = threadIdx.x;      // r in [0,512)
    const int base = tidx[i] * 50;
    bf16_t v = (bf16_t)0.0f;
    if (r >= base && r < base + 50)
        v = (bf16_t)(theta[i * 50 + (r - base)] / rsum[r]);
    T2[i * 512 + r] = v;
}

// ---------------- K4: out(256x50000)fp32 = T2(256x512) @ P-hat ------------
__global__ __launch_bounds__(256, 4)
void gemm_out(const bf16_t* __restrict__ T2, const bf16_t* __restrict__ Pt,
              float* __restrict__ out)
{
    __shared__ __align__(16) bf16_t As[256 * 64];   // 32 KB
    __shared__ __align__(16) bf16_t Bs[64 * 64];    // 8 KB
    const int tid = threadIdx.x;
    const int wave = tid >> 6, lane = tid & 63;
    const int bn0 = blockIdx.x * 64;
    const int lrow = lane & 15, q = lane >> 4;
    const int srow = lane >> 3, sgrp = (lane & 7) ^ srow;

    f32x4 acc[4][4] = {};

    for (int k0 = 0; k0 < 512; k0 += 64) {
#pragma unroll
        for (int cc = 0; cc < 8; ++cc) {            // A: 32 chunks total
            const int ch = wave * 8 + cc;
            GLDS(T2 + (ch * 8 + srow) * 512 + k0 + sgrp * 8, As + ch * 512);
        }
#pragma unroll
        for (int cc = 0; cc < 2; ++cc) {            // B: 8 chunks total
            const int ch = wave * 2 + cc;
            const long brow = bn0 + ch * 8 + srow;  // Pt padded to 50048 rows
            GLDS(Pt + brow * 512 + k0 + sgrp * 8, Bs + ch * 512);
        }
        __syncthreads();
#pragma unroll
        for (int kk = 0; kk < 2; ++kk) {
            const int kg = kk * 4 + q;
            bf16x8 af[4], bfr[4];
#pragma unroll
            for (int a = 0; a < 4; ++a) {
                const int row = wave * 64 + a * 16 + lrow;
                af[a] = *(const bf16x8*)(As + row * 64 + ((kg ^ (row & 7)) * 8));
            }
#pragma unroll
            for (int b = 0; b < 4; ++b) {
                const int n = b * 16 + lrow;
                bfr[b] = *(const bf16x8*)(Bs + n * 64 + ((kg ^ (n & 7)) * 8));
            }
#pragma unroll
            for (int a = 0; a < 4; ++a)
#pragma unroll
                for (int b = 0; b < 4; ++b)
                    acc[a][b] = MFMA16(af[a], bfr[b], acc[a][b]);
        }
        __syncthreads();
    }
#pragma unroll
    for (int a = 0; a < 4; ++a) {
        const int row0 = wave * 64 + a * 16 + q * 4;
#pragma unroll
        for (int b = 0; b < 4; ++b) {
            const int col = bn0 + b * 16 + lrow;
            if (col < 50000) {
#pragma unroll
                for (int r = 0; r < 4; ++r)
                    out[(long)(row0 + r) * 50000 + col] = acc[a][b][r];
            }
        }
    }
}

extern "C" void kernel_launch(void* const* d_in, const int* in_sizes, int n_in,
                              void* d_out, int out_size, void* d_ws, size_t ws_size,
                              hipStream_t stream)
{
    const float* theta = (const float*)d_in[0];   // (256,50) fp32
    const float* wemb  = (const float*)d_in[1];   // (50000,1024) fp32
    const float* temb  = (const float*)d_in[2];   // (500,1024) fp32
    const int*   tidx  = (const int*)d_in[3];     // (256,)
    float* out = (float*)d_out;                   // (256,50000) fp32

    char* ws = (char*)d_ws;
    bf16_t* Pt    = (bf16_t*)ws;                          // 50048*512*2 = 51,249,152
    float*  rsum  = (float*)(ws + 51249152);              // 2 KB
    bf16_t* a_hi  = (bf16_t*)(ws + 51251200);             // 1,024,000
    bf16_t* a_lo  = (bf16_t*)(ws + 52275200);             // 1,024,000
    bf16_t* T2    = (bf16_t*)(ws + 53299200);             // 262,144

    prep        <<<dim3(2000), 256, 0, stream>>>(temb, a_hi, a_lo, rsum);
    gemm_logits <<<dim3(1564), 512, 0, stream>>>(a_hi, a_lo, wemb, Pt, rsum);
    build_theta2<<<dim3(256),  512, 0, stream>>>(theta, tidx, rsum, T2);
    gemm_out    <<<dim3(782),  256, 0, stream>>>(T2, Pt, out);
}

// Round 3
// 464.620 us; speedup vs baseline: 1.0802x; 1.0481x over previous
//
#include <hip/hip_runtime.h>
#include <hip/hip_bf16.h>

// DTM decoder, fp32 in/out. Round-7 structure:
//   K0 prep        : temb fp32 -> A_hi/A_lo bf16; zero rowsum[512]
//   K1 gemm_logits : BM=128 BN=128 BK=64, 256 thr (4 waves, 2m x 2n), each
//                    wave owns a 64x64 tile (48 FLOP per LDS byte — LDS-read
//                    floor == MFMA floor). SINGLE 64KB LDS buffer -> 2
//                    independent blocks/CU (inter-block pipe overlap, m114).
//                    Load order: A-GLDS before cvt (L2-hot, hidden by cvt);
//                    W reg-prefetch(t+1) issued at top of compute phase
//                    (HBM latency hidden under MFMA, drained by end-sync).
//                    3-term bf16 split (Ah@Bh + Ah@Bl + Al@Bh). setprio.
//                    Chunked-bijective XCD swizzle (m204).
//                    Epilogue: P-hat=exp(l-180), atomicAdd rowsums, P-hat^T.
//   K3 build_theta2: T2[i, t_i*50+kap] = theta[i,kap]/rowsum -> (256,512) bf16
//   K4 gemm_out    : out(256,50000)fp32 = T2 @ P-hat — pure GLDS+b128 GEMM.
// ws: Pt(50048x512 bf16) | rowsum 2KB | a_hi 1MB | a_lo 1MB | T2 256KB ~53.5MB

typedef __bf16 bf16_t;
typedef __bf16 bf16x4 __attribute__((ext_vector_type(4)));
typedef __bf16 bf16x8 __attribute__((ext_vector_type(8)));
typedef float f32x4 __attribute__((ext_vector_type(4)));

typedef __attribute__((address_space(1))) void gvoid;
typedef __attribute__((address_space(3))) void svoid;
#define GLDS(SRC, DST) \
    __builtin_amdgcn_global_load_lds((gvoid*)(SRC), (svoid*)(DST), 16, 0, 0)
#define MFMA16(A, B, C) __builtin_amdgcn_mfma_f32_16x16x32_bf16((A), (B), (C), 0, 0, 0)

#define SHIFT 180.0f
#define TTS2 72  // per-wave transpose stride (64 k + 8 pad, 16B-aligned rows)

__device__ __forceinline__ void cvt8(float4 a, float4 b, bf16x8& h, bf16x8& l)
{
    float f[8] = {a.x, a.y, a.z, a.w, b.x, b.y, b.z, b.w};
#pragma unroll
    for (int j = 0; j < 8; ++j) {
        bf16_t hh = (bf16_t)f[j];
        h[j] = hh;
        l[j] = (bf16_t)(f[j] - (float)hh);
    }
}

// ---------------- K0: split A fp32 -> (hi,lo) bf16; zero rowsum ----------
__global__ void prep(const float* __restrict__ x, bf16_t* __restrict__ hi,
                     bf16_t* __restrict__ lo, float* __restrict__ rsum)
{
    int i = blockIdx.x * 256 + threadIdx.x;
    if (i < 512) rsum[i] = 0.f;
    if (i < 512000) {
        float v = x[i];
        bf16_t h = (bf16_t)v;
        hi[i] = h;
        lo[i] = (bf16_t)(v - (float)h);
    }
}

// ---------------- K1: 128x128 tile, 64x64/wave, single-buf, 2 blk/CU ------
// grid: 1564 linear blocks = 4 mtiles x 391 ntiles, XCD-chunk swizzled.
__global__ __launch_bounds__(256, 2)
void gemm_logits(const bf16_t* __restrict__ Ahi, const bf16_t* __restrict__ Alo,
                 const float* __restrict__ W, bf16_t* __restrict__ Pt,
                 float* __restrict__ Rsum)
{
    // AsH 16K | AsL 16K | BsH 16K | BsL 16K = 64 KB -> 2 blocks/CU
    __shared__ __align__(16) bf16_t sm[32768];
    bf16_t* AsH = sm;
    bf16_t* AsL = sm + 8192;
    bf16_t* BsH = sm + 16384;
    bf16_t* BsL = sm + 24576;

    const int tid = threadIdx.x;
    const int wv = tid >> 6, lane = tid & 63;
    const int wm = wv >> 1, wn = wv & 1;       // 2m x 2n wave grid, 64x64 each

    // chunked-bijective XCD swizzle (nwg=1564 = 8*195+4 -> q=195, r=4)
    const int lin = blockIdx.x;
    const int xcd = lin & 7, wi = lin >> 3;
    const int nid = (xcd < 4 ? xcd * 196 : 784 + (xcd - 4) * 195) + wi;
    const int bm0 = (nid & 3) * 128;
    const int bn0 = (nid >> 2) * 128;

    const int lrow = lane & 15, q = lane >> 4;
    const int srow = lane >> 3, sgrp = (lane & 7) ^ srow;

    // W staging role: 2 threads/row, 128 rows, 32 consecutive floats each
    const int wrow_l = tid >> 1;                // 0..127
    int wrow_g = bn0 + wrow_l; if (wrow_g > 49999) wrow_g = 49999;
    const int kq = tid & 1;                     // 32-float half-row
    const float4* wp = (const float4*)(W + (long)wrow_g * 1024) + kq * 8;
    int so[4];
#pragma unroll
    for (int jj = 0; jj < 4; ++jj)
        so[jj] = wrow_l * 64 + (((kq * 4 + jj) ^ (wrow_l & 7)) * 8);

    f32x4 acc[4][4] = {};
    float4 wcur[8], wnxt[8];
#pragma unroll
    for (int j = 0; j < 8; ++j) wcur[j] = wp[j];    // t=0 preload

    for (int t = 0; t < 16; ++t) {
        const int k0 = t * 64;
        // (1) A-tile async GLDS (L2-hot after first m-pass; latency hidden
        //     by the cvt phase below before the sync drains it)
#pragma unroll
        for (int cc = 0; cc < 4; ++cc) {
            const int ch = wv * 4 + cc;         // 8-row chunk id, 0..15
            int ar = bm0 + ch * 8 + srow; if (ar > 499) ar = 499;
            GLDS(Ahi + (long)ar * 1024 + k0 + sgrp * 8, AsH + ch * 512);
            GLDS(Alo + (long)ar * 1024 + k0 + sgrp * 8, AsL + ch * 512);
        }
        // (2) current W: split -> swizzled LDS (8 ds_write_b128)
#pragma unroll
        for (int jj = 0; jj < 4; ++jj) {
            bf16x8 h, l;
            cvt8(wcur[2 * jj], wcur[2 * jj + 1], h, l);
            *(bf16x8*)(BsH + so[jj]) = h;
            *(bf16x8*)(BsL + so[jj]) = l;
        }
        __syncthreads();
        // (3) W reg-prefetch for t+1 — issued at top of compute phase, HBM
        //     latency hidden under ~2000cy of MFMA, drained by the end-sync
        if (t < 15) {
            const int o = (t + 1) * 16;
#pragma unroll
            for (int j = 0; j < 8; ++j) wnxt[j] = wp[o + j];
        }
        // (4) compute: 2 x (16 ds_read_b128 -> 48 MFMA)
#pragma unroll
        for (int kk = 0; kk < 2; ++kk) {
            const int kg = kk * 4 + q;
            bf16x8 ah[4], al[4], bh[4], bl[4];
#pragma unroll
            for (int a = 0; a < 4; ++a) {
                const int row = wm * 64 + a * 16 + lrow;
                const int off = row * 64 + ((kg ^ (row & 7)) * 8);
                ah[a] = *(const bf16x8*)(AsH + off);
                al[a] = *(const bf16x8*)(AsL + off);
            }
#pragma unroll
            for (int b = 0; b < 4; ++b) {
                const int n = wn * 64 + b * 16 + lrow;
                const int off = n * 64 + ((kg ^ (n & 7)) * 8);
                bh[b] = *(const bf16x8*)(BsH + off);
                bl[b] = *(const bf16x8*)(BsL + off);
            }
            __builtin_amdgcn_s_setprio(1);
#pragma unroll
            for (int a = 0; a < 4; ++a)
#pragma unroll
                for (int b = 0; b < 4; ++b) {
                    acc[a][b] = MFMA16(ah[a], bh[b], acc[a][b]);
                    acc[a][b] = MFMA16(ah[a], bl[b], acc[a][b]);
                    acc[a][b] = MFMA16(al[a], bh[b], acc[a][b]);
                }
            __builtin_amdgcn_s_setprio(0);
        }
        __syncthreads();
        if (t < 15) {
#pragma unroll
            for (int j = 0; j < 8; ++j) wcur[j] = wnxt[j];
        }
    }

    // ---- epilogue: exp, rowsum atomics, P-hat^T store ----
    // wave (wm,wn) owns rows [bm0+wm*64, +64), cols [bn0+wn*64, +64)
#pragma unroll
    for (int a = 0; a < 4; ++a) {
        float rs[4] = {0.f, 0.f, 0.f, 0.f};
#pragma unroll
        for (int b = 0; b < 4; ++b) {
            const bool cok = (bn0 + wn * 64 + b * 16 + lrow) < 50000;
#pragma unroll
            for (int r = 0; r < 4; ++r) {
                const float e = __expf(acc[a][b][r] - SHIFT);
                acc[a][b][r] = e;
                if (cok) rs[r] += e;
            }
        }
#pragma unroll
        for (int r = 0; r < 4; ++r) {
            float v = rs[r];
            v += __shfl_xor(v, 1, 16);
            v += __shfl_xor(v, 2, 16);
            v += __shfl_xor(v, 4, 16);
            v += __shfl_xor(v, 8, 16);
            const int row = bm0 + wm * 64 + a * 16 + q * 4 + r;
            if (lrow == 0 && row < 500) atomicAdd(Rsum + row, v);
        }
    }
    // per-wave transpose: Tt[v_loc 0..63][k_loc 0..63]; 4 waves x 9216 B
    // (all frag reads done: both waves passed the loop's trailing sync)
    bf16_t* Tt = sm + wv * (64 * TTS2);
#pragma unroll
    for (int a = 0; a < 4; ++a)
#pragma unroll
        for (int b = 0; b < 4; ++b) {
            bf16x4 p;
#pragma unroll
            for (int r = 0; r < 4; ++r) p[r] = (bf16_t)acc[a][b][r];
            *(bf16x4*)(Tt + (b * 16 + lrow) * TTS2 + a * 16 + q * 4) = p;
        }
    // coalesced store: 8 lanes cover one v-row's 128B (64 k-elems)
    const long kbase = bm0 + wm * 64;
    const int cbase = bn0 + wn * 64;
#pragma unroll
    for (int it = 0; it < 8; ++it) {
        const int u = it * 64 + lane;
        const int vl = u >> 3, ck = u & 7;
        bf16x8 d = *(const bf16x8*)(Tt + vl * TTS2 + ck * 8);
        *(bf16x8*)(Pt + (long)(cbase + vl) * 512 + kbase + ck * 8) = d;
    }
}

// ---------------- K3: T2[i,r] = theta[i,r-50t]/rowsum[r] (else 0) ---------
__global__ void build_theta2(const float* __restrict__ theta,
                             const int* __restrict__ tidx,
                             const float* __restrict__ rsum,
                             bf16_t* __restrict__ T2)
{
    const int i = blockIdx.x, r = threadIdx.x;      // r in [0,512)
    const int base = tidx[i] * 50;
    bf16_t v = (bf16_t)0.0f;
    if (r >= base && r < base + 50)
        v = (bf16_t)(theta[i * 50 + (r - base)] / rsum[r]);
    T2[i * 512 + r] = v;
}

// ---------------- K4: out(256x50000)fp32 = T2(256x512) @ P-hat ------------
__global__ __launch_bounds__(256, 4)
void gemm_out(const bf16_t* __restrict__ T2, const bf16_t* __restrict__ Pt,
              float* __restrict__ out)
{
    __shared__ __align__(16) bf16_t As[256 * 64];   // 32 KB
    __shared__ __align__(16) bf16_t Bs[64 * 64];    // 8 KB
    const int tid = threadIdx.x;
    const int wave = tid >> 6, lane = tid & 63;
    const int bn0 = blockIdx.x * 64;
    const int lrow = lane & 15, q = lane >> 4;
    const int srow = lane >> 3, sgrp = (lane & 7) ^ srow;

    f32x4 acc[4][4] = {};

    for (int k0 = 0; k0 < 512; k0 += 64) {
#pragma unroll
        for (int cc = 0; cc < 8; ++cc) {            // A: 32 chunks total
            const int ch = wave * 8 + cc;
            GLDS(T2 + (ch * 8 + srow) * 512 + k0 + sgrp * 8, As + ch * 512);
        }
#pragma unroll
        for (int cc = 0; cc < 2; ++cc) {            // B: 8 chunks total
            const int ch = wave * 2 + cc;
            const long brow = bn0 + ch * 8 + srow;  // Pt padded to 50048 rows
            GLDS(Pt + brow * 512 + k0 + sgrp * 8, Bs + ch * 512);
        }
        __syncthreads();
#pragma unroll
        for (int kk = 0; kk < 2; ++kk) {
            const int kg = kk * 4 + q;
            bf16x8 af[4], bfr[4];
#pragma unroll
            for (int a = 0; a < 4; ++a) {
                const int row = wave * 64 + a * 16 + lrow;
                af[a] = *(const bf16x8*)(As + row * 64 + ((kg ^ (row & 7)) * 8));
            }
#pragma unroll
            for (int b = 0; b < 4; ++b) {
                const int n = b * 16 + lrow;
                bfr[b] = *(const bf16x8*)(Bs + n * 64 + ((kg ^ (n & 7)) * 8));
            }
#pragma unroll
            for (int a = 0; a < 4; ++a)
#pragma unroll
                for (int b = 0; b < 4; ++b)
                    acc[a][b] = MFMA16(af[a], bfr[b], acc[a][b]);
        }
        __syncthreads();
    }
#pragma unroll
    for (int a = 0; a < 4; ++a) {
        const int row0 = wave * 64 + a * 16 + q * 4;
#pragma unroll
        for (int b = 0; b < 4; ++b) {
            const int col = bn0 + b * 16 + lrow;
            if (col < 50000) {
#pragma unroll
                for (int r = 0; r < 4; ++r)
                    out[(long)(row0 + r) * 50000 + col] = acc[a][b][r];
            }
        }
    }
}

extern "C" void kernel_launch(void* const* d_in, const int* in_sizes, int n_in,
                              void* d_out, int out_size, void* d_ws, size_t ws_size,
                              hipStream_t stream)
{
    const float* theta = (const float*)d_in[0];   // (256,50) fp32
    const float* wemb  = (const float*)d_in[1];   // (50000,1024) fp32
    const float* temb  = (const float*)d_in[2];   // (500,1024) fp32
    const int*   tidx  = (const int*)d_in[3];     // (256,)
    float* out = (float*)d_out;                   // (256,50000) fp32

    char* ws = (char*)d_ws;
    bf16_t* Pt    = (bf16_t*)ws;                          // 50048*512*2 = 51,249,152
    float*  rsum  = (float*)(ws + 51249152);              // 2 KB
    bf16_t* a_hi  = (bf16_t*)(ws + 51251200);             // 1,024,000
    bf16_t* a_lo  = (bf16_t*)(ws + 52275200);             // 1,024,000
    bf16_t* T2    = (bf16_t*)(ws + 53299200);             // 262,144

    prep        <<<dim3(2000), 256, 0, stream>>>(temb, a_hi, a_lo, rsum);
    gemm_logits <<<dim3(1564), 256, 0, stream>>>(a_hi, a_lo, wemb, Pt, rsum);
    build_theta2<<<dim3(256),  512, 0, stream>>>(theta, tidx, rsum, T2);
    gemm_out    <<<dim3(782),  256, 0, stream>>>(T2, Pt, out);
}